// Round 13
// baseline (87.859 us; speedup 1.0000x reference)
//
#include <hip/hip_runtime.h>
#include <hip/hip_bf16.h>
#include <stdint.h>

typedef __attribute__((ext_vector_type(8))) short short8;
typedef __attribute__((ext_vector_type(4))) float f32x4;
typedef __attribute__((ext_vector_type(4))) unsigned short u16x4;

__device__ __forceinline__ float bf2f(unsigned short u) {
  union { unsigned int u; float f; } x; x.u = ((unsigned int)u) << 16; return x.f;
}
__device__ __forceinline__ unsigned short f2bf(float f) {
  union { float f; unsigned int u; } x; x.f = f;
  unsigned int u = x.u;
  return (unsigned short)((u + 0x7fffu + ((u >> 16) & 1u)) >> 16);
}

__device__ __forceinline__ void gload_lds16(const void* g, void* l) {
  __builtin_amdgcn_global_load_lds(
      (const __attribute__((address_space(1))) void*)g,
      (__attribute__((address_space(3))) void*)l, 16, 0, 0);
}

// ---- fp32 -> bf16 convert (X + weights) + ones-block init (one launch) -----
__global__ void cvt_all(const float* __restrict__ X,
                        const float* __restrict__ w0, const float* __restrict__ w1,
                        const float* __restrict__ w2, const float* __restrict__ w3,
                        unsigned short* __restrict__ Xb,
                        unsigned short* __restrict__ Wb,
                        unsigned short* __restrict__ Ones) {
  if (blockIdx.y == 0) {
    int i = (blockIdx.x * 256 + threadIdx.x) * 4;
    f32x4 f = *(const f32x4*)(X + i);
    u16x4 o = { f2bf(f[0]), f2bf(f[1]), f2bf(f[2]), f2bf(f[3]) };
    *(u16x4*)(Xb + i) = o;
  } else if (blockIdx.y == 1) {
    int wi = blockIdx.x >> 10;
    const float* s = wi == 0 ? w0 : wi == 1 ? w1 : wi == 2 ? w2 : w3;
    int j = ((blockIdx.x & 1023) * 256 + threadIdx.x) * 4;
    f32x4 f = *(const f32x4*)(s + j);
    u16x4 o = { f2bf(f[0]), f2bf(f[1]), f2bf(f[2]), f2bf(f[3]) };
    *(u16x4*)(Wb + ((size_t)wi << 20) + j) = o;
  } else {
    // Ones block: [16][2048] bf16 — row 0 = 1.0, rows 1..15 = 0
    if (blockIdx.x < 32) {
      int j = (blockIdx.x * 256 + threadIdx.x) * 4;
      unsigned short v = (j < 2048) ? (unsigned short)0x3F80 : (unsigned short)0;
      u16x4 o = { v, v, v, v };
      *(u16x4*)(Ones + j) = o;
    }
  }
}

// ------- Fused QKV GEMM, 128x(3x64) tiles, 2 blocks/CU, ring-3 --------------
// grid (16,32) = 512 blocks (2/CU), 256 threads = 4 waves.
// Block: A-tile 128x32 + stacked W-tile (3 z x 64 rows)x32 per K-step.
// LDS: (128+192)*32*2B = 20 KB/buf, ring-3 = 60 KB -> 2 blocks/CU. vmcnt(5).
// Wave: 64 rows x 96 stacked cols: 4 A-frags + 6 B-frags -> 24 MFMA, all
// uniform swapped (reg-dim walks features). Q,K packed u16x4; V 2B scatter.
__global__ __launch_bounds__(256, 2)
void gemm_qkv_fused(const unsigned short* __restrict__ A,
                    const unsigned short* __restrict__ Wbase,
                    const float* __restrict__ bq, const float* __restrict__ bk,
                    const float* __restrict__ bv,
                    unsigned short* __restrict__ obf) {
  const int K = 1024, NT = 32;
  constexpr int ASZ = 128 * 32;        // 4096 ushorts
  constexpr int BSZ = 192 * 32;        // 6144 ushorts
  constexpr int BUFSZ = ASZ + BSZ;     // 10240 ushorts = 20 KB
  __shared__ unsigned short lds[3 * BUFSZ];  // 60 KB

  // XCD swizzle: nwg = 512, divisible by 8 -> bijective
  int flat = blockIdx.y * 16 + blockIdx.x;
  int swz = (flat & 7) * 64 + (flat >> 3);
  const int n0 = (swz & 15) * 64, m0 = (swz >> 4) * 128;

  const int tid = threadIdx.x, lane = tid & 63, w = tid >> 6;
  const int wr = w >> 1, wc = w & 1;   // 64-row half, 96-stacked-col half
  const int fr = lane & 15, g = lane >> 4;

  f32x4 acc[4][6] = {};

#define STAGE_A(bi, t)                                                          \
  do {                                                                          \
    _Pragma("unroll") for (int i = 0; i < 2; ++i) {                             \
      int s = i * 256 + tid;                                                    \
      int row = s >> 2;                                                         \
      int gc = (s & 3) ^ ((row >> 1) & 3);                                      \
      gload_lds16(A + (size_t)(m0 + row) * K + (t) * 32 + gc * 8,               \
                  &lds[(bi) * BUFSZ + s * 8]);                                  \
    }                                                                           \
  } while (0)

#define STAGE_W(bi, t, i)                                                       \
  do {                                                                          \
    int s = (i) * 256 + tid;                                                    \
    int row = s >> 2;                                                           \
    int zz = row >> 6, br = row & 63;                                           \
    int gc = (s & 3) ^ ((row >> 1) & 3);                                        \
    gload_lds16(Wbase + ((size_t)zz << 20) + (size_t)(n0 + br) * K +            \
                    (t) * 32 + gc * 8,                                          \
                &lds[(bi) * BUFSZ + ASZ + s * 8]);                              \
  } while (0)

  STAGE_A(0, 0); STAGE_W(0, 0, 0); STAGE_W(0, 0, 1); STAGE_W(0, 0, 2);
  STAGE_A(1, 1); STAGE_W(1, 1, 0); STAGE_W(1, 1, 1); STAGE_W(1, 1, 2);

  for (int t = 0; t < NT; ++t) {
    if (t < NT - 1)
      asm volatile("s_waitcnt vmcnt(5)" ::: "memory");
    else
      asm volatile("s_waitcnt vmcnt(0)" ::: "memory");
    __builtin_amdgcn_s_barrier();
    __builtin_amdgcn_sched_barrier(0);

    const int bi = t % 3, bi2 = (t + 2) % 3;
    const bool pf = (t + 2 < NT);
    unsigned short* lb = lds + bi * BUFSZ;

    if (pf) STAGE_A(bi2, t + 2);

    short8 af[4];
#pragma unroll
    for (int m = 0; m < 4; ++m) {
      int ra = wr * 64 + m * 16 + fr;
      af[m] = *(const short8*)&lb[ra * 32 + ((g ^ ((ra >> 1) & 3)) * 8)];
    }
    if (pf) STAGE_W(bi2, t + 2, 0);
    short8 bfr[6];
#pragma unroll
    for (int n = 0; n < 3; ++n) {
      int rb2 = wc * 96 + n * 16 + fr;
      bfr[n] = *(const short8*)&lb[ASZ + rb2 * 32 + ((g ^ ((rb2 >> 1) & 3)) * 8)];
    }
    if (pf) STAGE_W(bi2, t + 2, 1);
#pragma unroll
    for (int n = 3; n < 6; ++n) {
      int rb2 = wc * 96 + n * 16 + fr;
      bfr[n] = *(const short8*)&lb[ASZ + rb2 * 32 + ((g ^ ((rb2 >> 1) & 3)) * 8)];
    }
    if (pf) STAGE_W(bi2, t + 2, 2);

    __builtin_amdgcn_s_setprio(1);
#pragma unroll
    for (int n = 0; n < 6; ++n)
#pragma unroll
      for (int m = 0; m < 4; ++m)
        acc[m][n] = __builtin_amdgcn_mfma_f32_16x16x32_bf16(bfr[n], af[m],
                                                            acc[m][n], 0, 0, 0);
    __builtin_amdgcn_s_setprio(0);
  }
#undef STAGE_A
#undef STAGE_W

  // epilogue: lane holds token=..+fr, features col0+g*4+i (z-stride 64)
#pragma unroll
  for (int m = 0; m < 4; ++m) {
#pragma unroll
    for (int n = 0; n < 6; ++n) {
      int base = wc * 96 + n * 16;       // stacked-col base (wave-uniform)
      int zz = base >> 6, brb = base & 63;
      int token = m0 + wr * 64 + m * 16 + fr;
      int bb = token >> 11, s0 = token & 2047;
      int col0 = n0 + brb + g * 4;
      if (zz < 2) {
        const float* bias = zz ? bk : bq;
        f32x4 bvv = *(const f32x4*)&bias[col0];
        u16x4 pk;
#pragma unroll
        for (int i = 0; i < 4; ++i) pk[i] = f2bf(acc[m][n][i] + bvv[i]);
        int hh = col0 >> 6, d0 = col0 & 63;
        *(u16x4*)&obf[(((size_t)(zz * 32 + bb * 16 + hh)) * 2048 + s0) * 64 + d0] = pk;
      } else {
        // V: reg-dim walks features -> scatter into V^T [b][h][d][s]
        f32x4 bvv = *(const f32x4*)&bv[col0];
#pragma unroll
        for (int i = 0; i < 4; ++i) {
          int col = col0 + i;
          int hh = col >> 6, d = col & 63;
          obf[(((size_t)(64 + bb * 16 + hh)) * 64 + d) * 2048 + s0] =
              f2bf(acc[m][n][i] + bvv[i]);
        }
      }
    }
  }
}

// ---- O-proj v2: 128x64 tiles, 512 blocks (2/CU), BK=64, ring-3, vmcnt(6) ---
__global__ __launch_bounds__(256)
void gemm_oproj(const unsigned short* __restrict__ A,
                const unsigned short* __restrict__ W,
                const float* __restrict__ bias, float* __restrict__ of32) {
  const int K = 1024, NT = 16;
  constexpr int ABUF = 128 * 64;
  constexpr int BBUF = 64 * 64;
  constexpr int BUFSZ = ABUF + BBUF;
  __shared__ unsigned short lds[3 * BUFSZ];  // 72 KB

  int flat = blockIdx.y * 16 + blockIdx.x;
  int swz = (flat & 7) * 64 + (flat >> 3);
  const int n0 = (swz & 15) * 64, m0 = (swz >> 4) * 128;

  const int tid = threadIdx.x, lane = tid & 63, w = tid >> 6;
  const int wr = w >> 1, wc = w & 1;
  const int fr = lane & 15, g = lane >> 4;

  f32x4 acc[4][2] = {};

#define STAGE(bi, t)                                                            \
  do {                                                                          \
    unsigned short* lb = lds + (bi) * BUFSZ;                                    \
    _Pragma("unroll") for (int i = 0; i < 4; ++i) {                             \
      int c = i * 256 + tid;                                                    \
      int row = c >> 3;                                                         \
      int ch = (c & 7) ^ (row & 7);                                             \
      gload_lds16(A + (size_t)(m0 + row) * K + (t) * 64 + ch * 8, &lb[c * 8]);  \
    }                                                                           \
    _Pragma("unroll") for (int i = 0; i < 2; ++i) {                             \
      int c = i * 256 + tid;                                                    \
      int row = c >> 3;                                                         \
      int ch = (c & 7) ^ (row & 7);                                             \
      gload_lds16(W + (size_t)(n0 + row) * K + (t) * 64 + ch * 8,               \
                  &lb[ABUF + c * 8]);                                           \
    }                                                                           \
  } while (0)

  STAGE(0, 0);
  STAGE(1, 1);
  for (int t = 0; t < NT; ++t) {
    if (t < NT - 1)
      asm volatile("s_waitcnt vmcnt(6)" ::: "memory");
    else
      asm volatile("s_waitcnt vmcnt(0)" ::: "memory");
    __builtin_amdgcn_s_barrier();
    __builtin_amdgcn_sched_barrier(0);
    if (t + 2 < NT) STAGE((t + 2) % 3, t + 2);

    unsigned short* lb = lds + (t % 3) * BUFSZ;
#pragma unroll
    for (int kk = 0; kk < 2; ++kk) {
      const int kc = kk * 4 + g;
      short8 af[4], bf[2];
#pragma unroll
      for (int m = 0; m < 4; ++m) {
        int ra = wr * 64 + m * 16 + fr;
        af[m] = *(const short8*)&lb[ra * 64 + ((kc ^ (ra & 7)) * 8)];
      }
#pragma unroll
      for (int n = 0; n < 2; ++n) {
        int rb = wc * 32 + n * 16 + fr;
        bf[n] = *(const short8*)&lb[ABUF + rb * 64 + ((kc ^ (rb & 7)) * 8)];
      }
      __builtin_amdgcn_s_setprio(1);
#pragma unroll
      for (int m = 0; m < 4; ++m)
#pragma unroll
        for (int n = 0; n < 2; ++n)
          acc[m][n] = __builtin_amdgcn_mfma_f32_16x16x32_bf16(bf[n], af[m],
                                                              acc[m][n], 0, 0, 0);
      __builtin_amdgcn_s_setprio(0);
    }
  }
#undef STAGE

#pragma unroll
  for (int m = 0; m < 4; ++m) {
#pragma unroll
    for (int n = 0; n < 2; ++n) {
      int token = m0 + wr * 64 + m * 16 + fr;
      int col0 = n0 + wc * 32 + n * 16 + g * 4;
      f32x4 bvv = *(const f32x4*)&bias[col0];
      f32x4 o;
#pragma unroll
      for (int i = 0; i < 4; ++i) o[i] = acc[m][n][i] + bvv[i];
      *(f32x4*)&of32[(size_t)token * 1024 + col0] = o;
    }
  }
}

// ------- MFMA flash attention, window=256, shuffle-free softmax -------------
__global__ __launch_bounds__(256)
void attn_mfma(const unsigned short* __restrict__ QKV,
               const unsigned short* __restrict__ Ones,
               unsigned short* __restrict__ AO) {
  const int S = 2048;
  const int b = blockIdx.z, h = blockIdx.y;
  const int q0 = blockIdx.x * 128;
  const size_t hb = (size_t)(b * 16 + h);
  const unsigned short* Qh = QKV + hb * (S * 64);
  const unsigned short* Kh = QKV + 4194304 + hb * (S * 64);
  const unsigned short* Vt = QKV + 8388608 + hb * (S * 64);  // [64][2048]

  const int tid = threadIdx.x;
  const int lane = tid & 63, w = tid >> 6;
  const int c = lane & 15, g = lane >> 4;
  const int qw0 = q0 + 32 * w;

  __shared__ unsigned short Plds[4][1024];
  char* Pb = (char*)&Plds[w][0];

  short8 qa[2][2];
#pragma unroll
  for (int mi = 0; mi < 2; ++mi)
#pragma unroll
    for (int cs = 0; cs < 2; ++cs)
      qa[mi][cs] = *(const short8*)(Qh + (size_t)(qw0 + 16 * mi + c) * 64 + 32 * cs + g * 8);

  f32x4 o[2][5] = {};

  int kt0 = qw0 - 256; if (kt0 < 0) kt0 = 0;
  const int ktlast = qw0;

  short8 kf[2][2], vf[5];
#pragma unroll
  for (int ni = 0; ni < 2; ++ni)
#pragma unroll
    for (int cs = 0; cs < 2; ++cs)
      kf[ni][cs] = *(const short8*)(Kh + (size_t)(kt0 + 16 * ni + c) * 64 + 32 * cs + g * 8);
#pragma unroll
  for (int ni = 0; ni < 4; ++ni)
    vf[ni] = *(const short8*)(Vt + (size_t)(16 * ni + c) * 2048 + kt0 + g * 8);
  vf[4] = *(const short8*)(Ones + (size_t)c * 2048 + kt0 + g * 8);

  for (int kt = kt0; kt <= ktlast; kt += 32) {
    const int ktn = (kt + 32 <= ktlast) ? kt + 32 : kt;
    short8 kfn[2][2], vfn[5];
#pragma unroll
    for (int ni = 0; ni < 2; ++ni)
#pragma unroll
      for (int cs = 0; cs < 2; ++cs)
        kfn[ni][cs] = *(const short8*)(Kh + (size_t)(ktn + 16 * ni + c) * 64 + 32 * cs + g * 8);
#pragma unroll
    for (int ni = 0; ni < 4; ++ni)
      vfn[ni] = *(const short8*)(Vt + (size_t)(16 * ni + c) * 2048 + ktn + g * 8);
    vfn[4] = *(const short8*)(Ones + (size_t)c * 2048 + ktn + g * 8);

    f32x4 sA[2][2] = {};
#pragma unroll
    for (int mi = 0; mi < 2; ++mi)
#pragma unroll
      for (int ni = 0; ni < 2; ++ni)
#pragma unroll
        for (int cs = 0; cs < 2; ++cs)
          sA[mi][ni] = __builtin_amdgcn_mfma_f32_16x16x32_bf16(qa[mi][cs], kf[ni][cs],
                                                               sA[mi][ni], 0, 0, 0);

#pragma unroll
    for (int mi = 0; mi < 2; ++mi) {
#pragma unroll
      for (int ni = 0; ni < 2; ++ni) {
#pragma unroll
        for (int r = 0; r < 4; ++r) {
          int q = qw0 + 16 * mi + 4 * g + r;
          int k = kt + 16 * ni + c;
          float p = ((unsigned)(q - k) <= 256u) ? __expf(sA[mi][ni][r] * 0.125f) : 0.f;
          int qloc = 16 * mi + 4 * g + r;
          int xr = (qloc & 12) << 2;
          *(unsigned short*)(Pb + ((qloc * 64 + ni * 32 + c * 2) ^ xr)) = f2bf(p);
        }
      }
    }

#pragma unroll
    for (int mi = 0; mi < 2; ++mi) {
      int qloc = 16 * mi + c;
      short8 pa = *(const short8*)(Pb + ((qloc * 64 + g * 16) ^ ((qloc & 12) << 2)));
#pragma unroll
      for (int ni = 0; ni < 5; ++ni)
        o[mi][ni] = __builtin_amdgcn_mfma_f32_16x16x32_bf16(pa, vf[ni], o[mi][ni], 0, 0, 0);
    }

#pragma unroll
    for (int ni = 0; ni < 2; ++ni)
#pragma unroll
      for (int cs = 0; cs < 2; ++cs)
        kf[ni][cs] = kfn[ni][cs];
#pragma unroll
    for (int ni = 0; ni < 5; ++ni)
      vf[ni] = vfn[ni];
  }

#pragma unroll
  for (int mi = 0; mi < 2; ++mi)
#pragma unroll
    for (int r = 0; r < 4; ++r) {
      float ls = __shfl(o[mi][4][r], lane & 48);
      float inv = 1.f / ls;
      int q = qw0 + 16 * mi + 4 * g + r;
      unsigned short* row = AO + (size_t)(b * 2048 + q) * 1024 + h * 64 + c;
#pragma unroll
      for (int ni = 0; ni < 4; ++ni)
        row[16 * ni] = f2bf(o[mi][ni][r] * inv);
    }
}

extern "C" void kernel_launch(void* const* d_in, const int* in_sizes, int n_in,
                              void* d_out, int out_size, void* d_ws, size_t ws_size,
                              hipStream_t stream) {
  const float* X  = (const float*)d_in[0];
  const float* wq = (const float*)d_in[1];
  const float* bq = (const float*)d_in[2];
  const float* wk = (const float*)d_in[3];
  const float* bk = (const float*)d_in[4];
  const float* wv = (const float*)d_in[5];
  const float* bv = (const float*)d_in[6];
  const float* wo = (const float*)d_in[7];
  const float* bo = (const float*)d_in[8];
  float* out = (float*)d_out;

  // ws (ushort elems): Xb[4.19M] | Wb[4x1.05M] | QKV[3x4.19M] | AO[4.19M] | Ones[32768]
  unsigned short* Xb   = (unsigned short*)d_ws;
  unsigned short* Wb   = Xb + 4194304;
  unsigned short* QKV  = Wb + 4194304;
  unsigned short* AO   = QKV + 12582912;
  unsigned short* Ones = AO + 4194304;

  cvt_all<<<dim3(4096, 3), dim3(256), 0, stream>>>(X, wq, wk, wv, wo, Xb, Wb, Ones);
  gemm_qkv_fused<<<dim3(16, 32), dim3(256), 0, stream>>>(Xb, Wb, bq, bk, bv, QKV);
  attn_mfma<<<dim3(16, 16, 2), dim3(256), 0, stream>>>(QKV, Ones, AO);
  gemm_oproj<<<dim3(16, 32), dim3(256), 0, stream>>>(AO, Wb + 3 * 1048576, bo, out);
}

// Round 14
// 82.206 us; speedup vs baseline: 1.0688x; 1.0688x over previous
//
#include <hip/hip_runtime.h>
#include <hip/hip_bf16.h>
#include <stdint.h>

typedef __attribute__((ext_vector_type(8))) short short8;
typedef __attribute__((ext_vector_type(4))) float f32x4;
typedef __attribute__((ext_vector_type(4))) unsigned short u16x4;

__device__ __forceinline__ float bf2f(unsigned short u) {
  union { unsigned int u; float f; } x; x.u = ((unsigned int)u) << 16; return x.f;
}
__device__ __forceinline__ unsigned short f2bf(float f) {
  union { float f; unsigned int u; } x; x.f = f;
  unsigned int u = x.u;
  return (unsigned short)((u + 0x7fffu + ((u >> 16) & 1u)) >> 16);
}

__device__ __forceinline__ void gload_lds16(const void* g, void* l) {
  __builtin_amdgcn_global_load_lds(
      (const __attribute__((address_space(1))) void*)g,
      (__attribute__((address_space(3))) void*)l, 16, 0, 0);
}

// ---- fp32 -> bf16 convert (X + all 4 weights, one launch) ------------------
__global__ void cvt_all(const float* __restrict__ X,
                        const float* __restrict__ w0, const float* __restrict__ w1,
                        const float* __restrict__ w2, const float* __restrict__ w3,
                        unsigned short* __restrict__ Xb,
                        unsigned short* __restrict__ Wb) {
  if (blockIdx.y == 0) {
    int i = (blockIdx.x * 256 + threadIdx.x) * 4;
    f32x4 f = *(const f32x4*)(X + i);
    u16x4 o = { f2bf(f[0]), f2bf(f[1]), f2bf(f[2]), f2bf(f[3]) };
    *(u16x4*)(Xb + i) = o;
  } else {
    int wi = blockIdx.x >> 10;
    const float* s = wi == 0 ? w0 : wi == 1 ? w1 : wi == 2 ? w2 : w3;
    int j = ((blockIdx.x & 1023) * 256 + threadIdx.x) * 4;
    f32x4 f = *(const f32x4*)(s + j);
    u16x4 o = { f2bf(f[0]), f2bf(f[1]), f2bf(f[2]), f2bf(f[3]) };
    *(u16x4*)(Wb + ((size_t)wi << 20) + j) = o;
  }
}

// ---------------- Fused QKV GEMM, fine-interleaved phases (R8/R10 version) --
__global__ __launch_bounds__(512, 2)
void gemm_qkv_fused(const unsigned short* __restrict__ A,
                    const unsigned short* __restrict__ Wbase,
                    const float* __restrict__ bq, const float* __restrict__ bk,
                    const float* __restrict__ bv,
                    unsigned short* __restrict__ obf) {
  const int K = 1024, NT = 32;
  constexpr int ASZ = 128 * 32;
  constexpr int BSZ = 3 * 128 * 32;
  __shared__ unsigned short lds[3 * (ASZ + BSZ)];  // 96 KB

  int flat = blockIdx.y * 8 + blockIdx.x;
  int swz = (flat & 7) * 32 + (flat >> 3);
  const int n0 = (swz & 7) * 128, m0 = (swz >> 3) * 128;

  const int tid = threadIdx.x, lane = tid & 63, w = tid >> 6;
  const int wr = w >> 1, wc = w & 1;
  const int fr = lane & 15, g = lane >> 4;

  f32x4 acc[3][2][4] = {};

#define STAGE_A(bi, t)                                                          \
  do {                                                                          \
    int s = tid;                                                                \
    int row = s >> 2;                                                           \
    int gc = (s & 3) ^ ((row >> 1) & 3);                                        \
    gload_lds16(A + (size_t)(m0 + row) * K + (t) * 32 + gc * 8,                 \
                &lds[(bi) * (ASZ + BSZ) + s * 8]);                              \
  } while (0)

#define STAGE_W(bi, t, i)                                                       \
  do {                                                                          \
    int s = (i) * 512 + tid;                                                    \
    int row = s >> 2;                                                           \
    int zz = row >> 7, br = row & 127;                                          \
    int gc = (s & 3) ^ ((row >> 1) & 3);                                        \
    gload_lds16(Wbase + ((size_t)zz << 20) + (size_t)(n0 + br) * K +            \
                    (t) * 32 + gc * 8,                                          \
                &lds[(bi) * (ASZ + BSZ) + ASZ + s * 8]);                        \
  } while (0)

  STAGE_A(0, 0); STAGE_W(0, 0, 0); STAGE_W(0, 0, 1); STAGE_W(0, 0, 2);
  STAGE_A(1, 1); STAGE_W(1, 1, 0); STAGE_W(1, 1, 1); STAGE_W(1, 1, 2);

  for (int t = 0; t < NT; ++t) {
    if (t < NT - 1)
      asm volatile("s_waitcnt vmcnt(4)" ::: "memory");
    else
      asm volatile("s_waitcnt vmcnt(0)" ::: "memory");
    __builtin_amdgcn_s_barrier();
    __builtin_amdgcn_sched_barrier(0);

    const int bi = t % 3, bi2 = (t + 2) % 3;
    const bool pf = (t + 2 < NT);
    unsigned short* lb = lds + bi * (ASZ + BSZ);

    if (pf) STAGE_A(bi2, t + 2);

    short8 af[2];
#pragma unroll
    for (int m = 0; m < 2; ++m) {
      int ra = wr * 32 + m * 16 + fr;
      af[m] = *(const short8*)&lb[ra * 32 + ((g ^ ((ra >> 1) & 3)) * 8)];
    }

#pragma unroll
    for (int zz = 0; zz < 3; ++zz) {
      short8 bfr[4];
#pragma unroll
      for (int n = 0; n < 4; ++n) {
        int rb2 = zz * 128 + wc * 64 + n * 16 + fr;
        bfr[n] = *(const short8*)&lb[ASZ + rb2 * 32 + ((g ^ ((rb2 >> 1) & 3)) * 8)];
      }
      if (pf) STAGE_W(bi2, t + 2, zz);
      __builtin_amdgcn_s_setprio(1);
#pragma unroll
      for (int m = 0; m < 2; ++m)
#pragma unroll
        for (int n = 0; n < 4; ++n) {
          if (zz < 2)
            acc[zz][m][n] = __builtin_amdgcn_mfma_f32_16x16x32_bf16(
                bfr[n], af[m], acc[zz][m][n], 0, 0, 0);
          else
            acc[zz][m][n] = __builtin_amdgcn_mfma_f32_16x16x32_bf16(
                af[m], bfr[n], acc[zz][m][n], 0, 0, 0);
        }
      __builtin_amdgcn_s_setprio(0);
    }
  }
#undef STAGE_A
#undef STAGE_W

#pragma unroll
  for (int zz = 0; zz < 2; ++zz) {
    const float* bias = zz == 0 ? bq : bk;
#pragma unroll
    for (int m = 0; m < 2; ++m) {
#pragma unroll
      for (int n = 0; n < 4; ++n) {
        int token = m0 + wr * 32 + m * 16 + fr;
        int col0 = n0 + wc * 64 + n * 16 + g * 4;
        f32x4 bvv = *(const f32x4*)&bias[col0];
        u16x4 pk;
#pragma unroll
        for (int i = 0; i < 4; ++i) pk[i] = f2bf(acc[zz][m][n][i] + bvv[i]);
        int hh = col0 >> 6, d0 = col0 & 63;
        int bb = token >> 11, s0 = token & 2047;
        *(u16x4*)&obf[(((size_t)(zz * 32 + bb * 16 + hh)) * 2048 + s0) * 64 + d0] = pk;
      }
    }
  }
#pragma unroll
  for (int m = 0; m < 2; ++m) {
#pragma unroll
    for (int n = 0; n < 4; ++n) {
      int col = n0 + wc * 64 + n * 16 + fr;
      float bias_v = bv[col];
      int row0 = m0 + wr * 32 + m * 16 + g * 4;
      int hh = col >> 6, d = col & 63;
      int bb = row0 >> 11, s0 = row0 & 2047;
      u16x4 pk;
#pragma unroll
      for (int i = 0; i < 4; ++i) pk[i] = f2bf(acc[2][m][n][i] + bias_v);
      *(u16x4*)&obf[(((size_t)(64 + bb * 16 + hh)) * 64 + d) * 2048 + s0] = pk;
    }
  }
}

// ---------------- O-proj: 128x128 tile, 8 waves, wave-level K-split (R10) ---
__global__ __launch_bounds__(512, 2)
void gemm_oproj(const unsigned short* __restrict__ A,
                const unsigned short* __restrict__ W,
                const float* __restrict__ bias, float* __restrict__ of32) {
  const int K = 1024, NT = 16;
  constexpr int ABUF = 128 * 64;
  constexpr int BUFSZ = 2 * ABUF;
  __shared__ unsigned short lds[3 * BUFSZ];  // 96 KB

  int flat = blockIdx.y * 8 + blockIdx.x;
  int swz = (flat & 7) * 32 + (flat >> 3);
  const int n0 = (swz & 7) * 128, m0 = (swz >> 3) * 128;

  const int tid = threadIdx.x, lane = tid & 63, w = tid >> 6;
  const int kg = w >> 2, wq = w & 3;
  const int mt = (wq >> 1) * 64, nt = (wq & 1) * 64;
  const int fr = lane & 15, g = lane >> 4;

  f32x4 acc[4][4] = {};

#define STAGE(bi, t)                                                            \
  do {                                                                          \
    unsigned short* lb = lds + (bi) * BUFSZ;                                    \
    _Pragma("unroll") for (int i = 0; i < 2; ++i) {                             \
      int c = i * 512 + tid;                                                    \
      int row = c >> 3;                                                         \
      int ch = (c & 7) ^ (row & 7);                                             \
      gload_lds16(A + (size_t)(m0 + row) * K + (t) * 64 + ch * 8, &lb[c * 8]);  \
    }                                                                           \
    _Pragma("unroll") for (int i = 0; i < 2; ++i) {                             \
      int c = i * 512 + tid;                                                    \
      int row = c >> 3;                                                         \
      int ch = (c & 7) ^ (row & 7);                                             \
      gload_lds16(W + (size_t)(n0 + row) * K + (t) * 64 + ch * 8,               \
                  &lb[ABUF + c * 8]);                                           \
    }                                                                           \
  } while (0)

  STAGE(0, 0);
  STAGE(1, 1);
  const int kc = kg * 4 + g;
  for (int t = 0; t < NT; ++t) {
    if (t < NT - 1)
      asm volatile("s_waitcnt vmcnt(4)" ::: "memory");
    else
      asm volatile("s_waitcnt vmcnt(0)" ::: "memory");
    __builtin_amdgcn_s_barrier();
    __builtin_amdgcn_sched_barrier(0);
    if (t + 2 < NT) STAGE((t + 2) % 3, t + 2);

    unsigned short* lb = lds + (t % 3) * BUFSZ;
    short8 af[4], bf[4];
#pragma unroll
    for (int m = 0; m < 4; ++m) {
      int ra = mt + m * 16 + fr;
      af[m] = *(const short8*)&lb[ra * 64 + ((kc ^ (ra & 7)) * 8)];
    }
#pragma unroll
    for (int n = 0; n < 4; ++n) {
      int rb = nt + n * 16 + fr;
      bf[n] = *(const short8*)&lb[ABUF + rb * 64 + ((kc ^ (rb & 7)) * 8)];
    }
    __builtin_amdgcn_s_setprio(1);
#pragma unroll
    for (int m = 0; m < 4; ++m)
#pragma unroll
      for (int n = 0; n < 4; ++n)
        acc[m][n] = __builtin_amdgcn_mfma_f32_16x16x32_bf16(bf[n], af[m],
                                                            acc[m][n], 0, 0, 0);
    __builtin_amdgcn_s_setprio(0);
  }
#undef STAGE

  __syncthreads();
  float* red = (float*)lds;
  if (kg == 1) {
#pragma unroll
    for (int m = 0; m < 4; ++m)
#pragma unroll
      for (int n = 0; n < 4; ++n)
        *(f32x4*)(red + wq * 4096 + (m * 4 + n) * 256 + lane * 4) = acc[m][n];
  }
  __syncthreads();
  if (kg == 0) {
#pragma unroll
    for (int m = 0; m < 4; ++m) {
#pragma unroll
      for (int n = 0; n < 4; ++n) {
        f32x4 other = *(const f32x4*)(red + wq * 4096 + (m * 4 + n) * 256 + lane * 4);
        int token = m0 + mt + m * 16 + fr;
        int col0 = n0 + nt + n * 16 + g * 4;
        f32x4 bvv = *(const f32x4*)&bias[col0];
        f32x4 o;
#pragma unroll
        for (int i = 0; i < 4; ++i) o[i] = acc[m][n][i] + other[i] + bvv[i];
        *(f32x4*)&of32[(size_t)token * 1024 + col0] = o;
      }
    }
  }
}

// ------- MFMA flash attention, window=256, shuffle-free softmax -------------
// Row-sum via 5th PV MFMA against a CONSTANT ones-fragment (lane c==0 holds
// 1.0s) — no Ones buffer, no global loads for it.
__global__ __launch_bounds__(256)
void attn_mfma(const unsigned short* __restrict__ QKV,
               unsigned short* __restrict__ AO) {
  const int S = 2048;
  const int b = blockIdx.z, h = blockIdx.y;
  const int q0 = blockIdx.x * 128;
  const size_t hb = (size_t)(b * 16 + h);
  const unsigned short* Qh = QKV + hb * (S * 64);
  const unsigned short* Kh = QKV + 4194304 + hb * (S * 64);
  const unsigned short* Vt = QKV + 8388608 + hb * (S * 64);  // [64][2048]

  const int tid = threadIdx.x;
  const int lane = tid & 63, w = tid >> 6;
  const int c = lane & 15, g = lane >> 4;
  const int qw0 = q0 + 32 * w;

  __shared__ unsigned short Plds[4][1024];
  char* Pb = (char*)&Plds[w][0];

  short8 qa[2][2];
#pragma unroll
  for (int mi = 0; mi < 2; ++mi)
#pragma unroll
    for (int cs = 0; cs < 2; ++cs)
      qa[mi][cs] = *(const short8*)(Qh + (size_t)(qw0 + 16 * mi + c) * 64 + 32 * cs + g * 8);

  // constant ones B-fragment: B[row=c][k] = (c==0) ? 1 : 0, independent of kt
  short8 vones;
  {
    short v = (c == 0) ? (short)0x3F80 : (short)0;
#pragma unroll
    for (int i = 0; i < 8; ++i) vones[i] = v;
  }

  f32x4 o[2][5] = {};

  int kt0 = qw0 - 256; if (kt0 < 0) kt0 = 0;
  const int ktlast = qw0;

  short8 kf[2][2], vf[4];
#pragma unroll
  for (int ni = 0; ni < 2; ++ni)
#pragma unroll
    for (int cs = 0; cs < 2; ++cs)
      kf[ni][cs] = *(const short8*)(Kh + (size_t)(kt0 + 16 * ni + c) * 64 + 32 * cs + g * 8);
#pragma unroll
  for (int ni = 0; ni < 4; ++ni)
    vf[ni] = *(const short8*)(Vt + (size_t)(16 * ni + c) * 2048 + kt0 + g * 8);

  for (int kt = kt0; kt <= ktlast; kt += 32) {
    const int ktn = (kt + 32 <= ktlast) ? kt + 32 : kt;
    short8 kfn[2][2], vfn[4];
#pragma unroll
    for (int ni = 0; ni < 2; ++ni)
#pragma unroll
      for (int cs = 0; cs < 2; ++cs)
        kfn[ni][cs] = *(const short8*)(Kh + (size_t)(ktn + 16 * ni + c) * 64 + 32 * cs + g * 8);
#pragma unroll
    for (int ni = 0; ni < 4; ++ni)
      vfn[ni] = *(const short8*)(Vt + (size_t)(16 * ni + c) * 2048 + ktn + g * 8);

    f32x4 sA[2][2] = {};
#pragma unroll
    for (int mi = 0; mi < 2; ++mi)
#pragma unroll
      for (int ni = 0; ni < 2; ++ni)
#pragma unroll
        for (int cs = 0; cs < 2; ++cs)
          sA[mi][ni] = __builtin_amdgcn_mfma_f32_16x16x32_bf16(qa[mi][cs], kf[ni][cs],
                                                               sA[mi][ni], 0, 0, 0);

#pragma unroll
    for (int mi = 0; mi < 2; ++mi) {
#pragma unroll
      for (int ni = 0; ni < 2; ++ni) {
#pragma unroll
        for (int r = 0; r < 4; ++r) {
          int q = qw0 + 16 * mi + 4 * g + r;
          int k = kt + 16 * ni + c;
          float p = ((unsigned)(q - k) <= 256u) ? __expf(sA[mi][ni][r] * 0.125f) : 0.f;
          int qloc = 16 * mi + 4 * g + r;
          int xr = (qloc & 12) << 2;
          *(unsigned short*)(Pb + ((qloc * 64 + ni * 32 + c * 2) ^ xr)) = f2bf(p);
        }
      }
    }

#pragma unroll
    for (int mi = 0; mi < 2; ++mi) {
      int qloc = 16 * mi + c;
      short8 pa = *(const short8*)(Pb + ((qloc * 64 + g * 16) ^ ((qloc & 12) << 2)));
#pragma unroll
      for (int ni = 0; ni < 4; ++ni)
        o[mi][ni] = __builtin_amdgcn_mfma_f32_16x16x32_bf16(pa, vf[ni], o[mi][ni], 0, 0, 0);
      o[mi][4] = __builtin_amdgcn_mfma_f32_16x16x32_bf16(pa, vones, o[mi][4], 0, 0, 0);
    }

#pragma unroll
    for (int ni = 0; ni < 2; ++ni)
#pragma unroll
      for (int cs = 0; cs < 2; ++cs)
        kf[ni][cs] = kfn[ni][cs];
#pragma unroll
    for (int ni = 0; ni < 4; ++ni)
      vf[ni] = vfn[ni];
  }

#pragma unroll
  for (int mi = 0; mi < 2; ++mi)
#pragma unroll
    for (int r = 0; r < 4; ++r) {
      float ls = __shfl(o[mi][4][r], lane & 48);
      float inv = 1.f / ls;
      int q = qw0 + 16 * mi + 4 * g + r;
      unsigned short* row = AO + (size_t)(b * 2048 + q) * 1024 + h * 64 + c;
#pragma unroll
      for (int ni = 0; ni < 4; ++ni)
        row[16 * ni] = f2bf(o[mi][ni][r] * inv);
    }
}

extern "C" void kernel_launch(void* const* d_in, const int* in_sizes, int n_in,
                              void* d_out, int out_size, void* d_ws, size_t ws_size,
                              hipStream_t stream) {
  const float* X  = (const float*)d_in[0];
  const float* wq = (const float*)d_in[1];
  const float* bq = (const float*)d_in[2];
  const float* wk = (const float*)d_in[3];
  const float* bk = (const float*)d_in[4];
  const float* wv = (const float*)d_in[5];
  const float* bv = (const float*)d_in[6];
  const float* wo = (const float*)d_in[7];
  const float* bo = (const float*)d_in[8];
  float* out = (float*)d_out;

  // ws (ushort elems): Xb[4.19M] | Wb[4x1.05M] | QKV[3x4.19M] | AO[4.19M]
  unsigned short* Xb  = (unsigned short*)d_ws;
  unsigned short* Wb  = Xb + 4194304;
  unsigned short* QKV = Wb + 4194304;
  unsigned short* AO  = QKV + 12582912;

  cvt_all<<<dim3(4096, 2), dim3(256), 0, stream>>>(X, wq, wk, wv, wo, Xb, Wb);
  gemm_qkv_fused<<<dim3(8, 32), dim3(512), 0, stream>>>(Xb, Wb, bq, bk, bv, QKV);
  attn_mfma<<<dim3(16, 16, 2), dim3(256), 0, stream>>>(QKV, AO);
  gemm_oproj<<<dim3(8, 32), dim3(512), 0, stream>>>(AO, Wb + 3 * 1048576, bo, out);
}